// Round 7
// baseline (32.458 us; speedup 1.0000x reference)
//
#include <hip/hip_runtime.h>

// Problem constants (B, L, D from reference)
#define BB 64
#define LL 4096
#define DD 256
#define D4 (DD / 4)        // float4 per row = 64
#define RPC 32             // rows per chunk
#define CPB 4              // waves (chunks) per block, phase 1
#define GRID1 2048         // phase-1 blocks: 8192 wave slots >= max A = 64*128
#define RWAVES 8           // waves per block, phase 2

// Per-block scan: pref[b] = sum_{b'<b} ceil(len[b']/RPC); pref[BB] = total A.
// Wave 0 does a 64-lane shfl scan; everyone reads from LDS after the barrier.
__device__ __forceinline__ void scan_prefix(const int* __restrict__ len,
                                            int* pref, int tid) {
    if (tid < 64) {
        int lb = len[tid];
        if (lb < 1) lb = 1;
        int s = (lb + RPC - 1) >> 5;         // ceil(lb/32)
        #pragma unroll
        for (int d = 1; d < 64; d <<= 1) {
            int t = __shfl_up(s, d, 64);
            if (tid >= d) s += t;
        }
        pref[tid + 1] = s;
        if (tid == 0) pref[0] = 0;
    }
    __syncthreads();
}

// ---------------- Phase 1: globally balanced partial sums ----------------
// Global wave-slot g = blockIdx*4 + wave handles ACTIVE chunk g (g < A).
// Every active slot does exactly one 32-row chunk -> per-CU bytes uniform
// regardless of the length distribution. Partial -> ws[g].
__global__ __launch_bounds__(256) void avg_partial_kernel(
    const float* __restrict__ in,        // [B, L, D]
    const int* __restrict__ len,         // [B] (int32)
    float* __restrict__ ws)              // [A, D] slots
{
    __shared__ int pref[BB + 1];
    const int tid = threadIdx.x;
    scan_prefix(len, pref, tid);

    const int A    = pref[BB];
    const int w    = tid >> 6;
    const int lane = tid & 63;
    const int g    = blockIdx.x * CPB + w;
    if (g >= A) return;                  // after the only barrier — safe

    // binary search: pref[b] <= g < pref[b+1]  (wave-uniform -> LDS broadcast)
    int lo = 0, hi = BB;
    while (hi - lo > 1) {
        int mid = (lo + hi) >> 1;
        if (pref[mid] <= g) lo = mid; else hi = mid;
    }
    const int b = lo;
    const int p = g - pref[b];

    int lb = len[b];
    if (lb < 1) lb = 1;
    const int row0 = p * RPC;
    int n = lb - row0;
    if (n > RPC) n = RPC;

    const float4* __restrict__ base =
        (const float4*)(in + (size_t)b * LL * DD) + (size_t)row0 * D4 + lane;

    float4 acc = make_float4(0.f, 0.f, 0.f, 0.f);
    #pragma unroll 8
    for (int r = 0; r < n; ++r) {
        float4 v = base[(size_t)r * D4];
        acc.x += v.x; acc.y += v.y; acc.z += v.z; acc.w += v.w;
    }

    ((float4*)ws)[(size_t)g * D4 + lane] = acc;
}

// ---------------- Phase 2: reduce ws[pref[b]..pref[b+1]), divide by len ----------------
__global__ __launch_bounds__(512) void avg_reduce_kernel(
    const float* __restrict__ ws,
    const int* __restrict__ len,
    float* __restrict__ out)             // [B, D]
{
    __shared__ int pref[BB + 1];
    const int tid = threadIdx.x;
    scan_prefix(len, pref, tid);

    const int b    = blockIdx.x;
    const int w    = tid >> 6;
    const int lane = tid & 63;
    const int g0   = pref[b];
    const int g1   = pref[b + 1];

    float4 acc = make_float4(0.f, 0.f, 0.f, 0.f);
    for (int g = g0 + w; g < g1; g += RWAVES) {
        float4 v = ((const float4*)ws)[(size_t)g * D4 + lane];
        acc.x += v.x; acc.y += v.y; acc.z += v.z; acc.w += v.w;
    }

    __shared__ float4 sh[RWAVES - 1][64];
    if (w > 0) sh[w - 1][lane] = acc;
    __syncthreads();

    if (w == 0) {
        #pragma unroll
        for (int i = 0; i < RWAVES - 1; ++i) {
            float4 v = sh[i][lane];
            acc.x += v.x; acc.y += v.y; acc.z += v.z; acc.w += v.w;
        }
        int lb = len[b];
        if (lb < 1) lb = 1;
        const float inv = 1.0f / (float)lb;
        float4 o = make_float4(acc.x * inv, acc.y * inv, acc.z * inv, acc.w * inv);
        ((float4*)out)[(size_t)b * D4 + lane] = o;
    }
}

// ---------------- Fallback (tiny ws): zero-out + atomic accumulate ----------------
__global__ void avg_zero_out_kernel(float* __restrict__ out) {
    int i = blockIdx.x * blockDim.x + threadIdx.x;
    if (i < BB * DD) out[i] = 0.f;
}

__global__ __launch_bounds__(64) void avg_atomic_kernel(
    const float* __restrict__ in,
    const int* __restrict__ len,
    float* __restrict__ out)
{
    const int b    = blockIdx.x >> 6;
    const int p    = blockIdx.x & 63;
    const int lane = threadIdx.x;

    int lb = len[b];
    if (lb < 1) lb = 1;
    const int row0 = p * 64;
    int rend = row0 + 64;
    if (rend > lb) rend = (lb > row0) ? lb : row0;
    if (rend <= row0) return;

    float4 acc = make_float4(0.f, 0.f, 0.f, 0.f);
    const float4* __restrict__ base = (const float4*)(in + (size_t)b * LL * DD);
    for (int r = row0; r < rend; ++r) {
        float4 v = base[(size_t)r * D4 + lane];
        acc.x += v.x; acc.y += v.y; acc.z += v.z; acc.w += v.w;
    }
    const float inv = 1.0f / (float)lb;
    float* o = out + (size_t)b * DD + lane * 4;
    atomicAdd(o + 0, acc.x * inv);
    atomicAdd(o + 1, acc.y * inv);
    atomicAdd(o + 2, acc.z * inv);
    atomicAdd(o + 3, acc.w * inv);
}

extern "C" void kernel_launch(void* const* d_in, const int* in_sizes, int n_in,
                              void* d_out, int out_size, void* d_ws, size_t ws_size,
                              hipStream_t stream) {
    const float* in  = (const float*)d_in[0];
    const int*   len = (const int*)d_in[1];
    float*       out = (float*)d_out;

    // ws: up to A = 64*128 = 8192 chunk-partials of D floats = 8 MiB
    const size_t ws_needed = (size_t)(BB * (LL / RPC)) * DD * sizeof(float);

    if (d_ws != nullptr && ws_size >= ws_needed) {
        float* ws = (float*)d_ws;
        avg_partial_kernel<<<GRID1, 64 * CPB, 0, stream>>>(in, len, ws);
        avg_reduce_kernel<<<BB, 64 * RWAVES, 0, stream>>>(ws, len, out);
    } else {
        avg_zero_out_kernel<<<(BB * DD + 255) / 256, 256, 0, stream>>>(out);
        avg_atomic_kernel<<<BB * 64, 64, 0, stream>>>(in, len, out);
    }
}

// Round 8
// 28.748 us; speedup vs baseline: 1.1290x; 1.1290x over previous
//
#include <hip/hip_runtime.h>

// Problem constants (B, L, D from reference)
#define BB 64
#define LL 4096
#define DD 256
#define D4 (DD / 4)        // float4 per row = 64
#define RPC 32             // rows per chunk (one wave's work)
#define CPB 4              // chunks (waves) per block
#define ROWS_PER_BLOCK (RPC * CPB)   // 128
#define BPB (LL / ROWS_PER_BLOCK)    // blocks per batch = 32
#define RWAVES 8           // waves per block, phase 2

// ---------------- Phase 1: partial sums, block-combined ----------------
// 2048 blocks x 256 threads (8 blocks/CU = 32 waves/CU, max TLP).
// Block covers 128 adjacent rows of ONE batch; wave w streams 32 rows
// (float4/lane, coalesced, unroll 8 -> 8 loads in flight). The 4 waves are
// LDS-combined and wave 0 writes ONE partial per block -> ws is 2 MiB
// (was 8 MiB unreduced), cutting the ws round-trip from 16 to 4 MiB.
__global__ __launch_bounds__(256) void avg_partial_kernel(
    const float* __restrict__ in,        // [B, L, D]
    const int* __restrict__ len,         // [B] (int32)
    float* __restrict__ ws)              // [B, BPB, D]
{
    const int w    = threadIdx.x >> 6;   // wave 0..3
    const int lane = threadIdx.x & 63;
    const int b    = blockIdx.x / BPB;   // batch (b-major, proven R5)
    const int s    = blockIdx.x % BPB;   // block slot within batch

    int lb = len[b];
    if (lb < 1) lb = 1;

    // Whole-block inactive? (block-uniform -> safe early exit, slot never read)
    if (s * ROWS_PER_BLOCK >= lb) return;

    const int row0 = s * ROWS_PER_BLOCK + w * RPC;

    float4 acc = make_float4(0.f, 0.f, 0.f, 0.f);
    if (row0 < lb) {
        int n = lb - row0;
        if (n > RPC) n = RPC;
        const float4* __restrict__ base =
            (const float4*)(in + (size_t)b * LL * DD) + (size_t)row0 * D4 + lane;
        #pragma unroll 8
        for (int r = 0; r < n; ++r) {
            float4 v = base[(size_t)r * D4];
            acc.x += v.x; acc.y += v.y; acc.z += v.z; acc.w += v.w;
        }
    }

    __shared__ float4 sh[CPB - 1][64];
    if (w > 0) sh[w - 1][lane] = acc;
    __syncthreads();

    if (w == 0) {
        #pragma unroll
        for (int i = 0; i < CPB - 1; ++i) {
            float4 v = sh[i][lane];
            acc.x += v.x; acc.y += v.y; acc.z += v.z; acc.w += v.w;
        }
        ((float4*)ws)[((size_t)b * BPB + s) * D4 + lane] = acc;
    }
}

// ---------------- Phase 2: reduce <=32 block partials, divide by length ----------------
// 64 blocks x 512 threads (8 waves): wave w reads slots w, w+8, ... (<=4 loads),
// LDS combine, wave 0 scales and writes out.
__global__ __launch_bounds__(512) void avg_reduce_kernel(
    const float* __restrict__ ws,        // [B, BPB, D]
    const int* __restrict__ len,         // [B]
    float* __restrict__ out)             // [B, D]
{
    const int b    = blockIdx.x;
    const int w    = threadIdx.x >> 6;
    const int lane = threadIdx.x & 63;

    int lb = len[b];
    if (lb < 1) lb = 1;
    const int nslots = (lb + ROWS_PER_BLOCK - 1) / ROWS_PER_BLOCK;  // 1..32

    float4 acc = make_float4(0.f, 0.f, 0.f, 0.f);
    const float4* __restrict__ wsb = (const float4*)ws + (size_t)b * BPB * D4;

    #pragma unroll 4
    for (int s = w; s < nslots; s += RWAVES) {
        float4 v = wsb[(size_t)s * D4 + lane];
        acc.x += v.x; acc.y += v.y; acc.z += v.z; acc.w += v.w;
    }

    __shared__ float4 sh[RWAVES - 1][64];
    if (w > 0) sh[w - 1][lane] = acc;
    __syncthreads();

    if (w == 0) {
        #pragma unroll
        for (int i = 0; i < RWAVES - 1; ++i) {
            float4 v = sh[i][lane];
            acc.x += v.x; acc.y += v.y; acc.z += v.z; acc.w += v.w;
        }
        const float inv = 1.0f / (float)lb;
        float4 o = make_float4(acc.x * inv, acc.y * inv, acc.z * inv, acc.w * inv);
        ((float4*)out)[(size_t)b * D4 + lane] = o;
    }
}

// ---------------- Fallback (tiny ws): zero-out + atomic accumulate ----------------
__global__ void avg_zero_out_kernel(float* __restrict__ out) {
    int i = blockIdx.x * blockDim.x + threadIdx.x;
    if (i < BB * DD) out[i] = 0.f;
}

__global__ __launch_bounds__(64) void avg_atomic_kernel(
    const float* __restrict__ in,
    const int* __restrict__ len,
    float* __restrict__ out)
{
    const int b    = blockIdx.x >> 6;
    const int p    = blockIdx.x & 63;
    const int lane = threadIdx.x;

    int lb = len[b];
    if (lb < 1) lb = 1;
    const int row0 = p * 64;
    int rend = row0 + 64;
    if (rend > lb) rend = (lb > row0) ? lb : row0;
    if (rend <= row0) return;

    float4 acc = make_float4(0.f, 0.f, 0.f, 0.f);
    const float4* __restrict__ base = (const float4*)(in + (size_t)b * LL * DD);
    for (int r = row0; r < rend; ++r) {
        float4 v = base[(size_t)r * D4 + lane];
        acc.x += v.x; acc.y += v.y; acc.z += v.z; acc.w += v.w;
    }
    const float inv = 1.0f / (float)lb;
    float* o = out + (size_t)b * DD + lane * 4;
    atomicAdd(o + 0, acc.x * inv);
    atomicAdd(o + 1, acc.y * inv);
    atomicAdd(o + 2, acc.z * inv);
    atomicAdd(o + 3, acc.w * inv);
}

extern "C" void kernel_launch(void* const* d_in, const int* in_sizes, int n_in,
                              void* d_out, int out_size, void* d_ws, size_t ws_size,
                              hipStream_t stream) {
    const float* in  = (const float*)d_in[0];
    const int*   len = (const int*)d_in[1];
    float*       out = (float*)d_out;

    const size_t ws_needed = (size_t)BB * BPB * DD * sizeof(float); // 2 MiB

    if (d_ws != nullptr && ws_size >= ws_needed) {
        float* ws = (float*)d_ws;
        avg_partial_kernel<<<BB * BPB, 64 * CPB, 0, stream>>>(in, len, ws);
        avg_reduce_kernel<<<BB, 64 * RWAVES, 0, stream>>>(ws, len, out);
    } else {
        avg_zero_out_kernel<<<(BB * DD + 255) / 256, 256, 0, stream>>>(out);
        avg_atomic_kernel<<<BB * 64, 64, 0, stream>>>(in, len, out);
    }
}